// Round 2
// baseline (578.429 us; speedup 1.0000x reference)
//
#include <hip/hip_runtime.h>
#include <hip/hip_bf16.h>
#include <math.h>

#define T_LEN 4096
#define NB    64
#define DH    64
#define NTH   512
#define EPS   1e-6f

__global__ __launch_bounds__(NTH)
void sortnet_fused(const float* __restrict__ q,
                   const float* __restrict__ k,
                   const int*   __restrict__ seg,
                   const float* __restrict__ u,
                   float*       __restrict__ out)
{
    const int b    = blockIdx.x;
    const int tid  = threadIdx.x;
    const int wave = tid >> 6;
    const int lane = tid & 63;

    __shared__ float qs [NB][DH];        // q bucket sums [i][d]
    __shared__ float kst[DH][NB + 1];    // k bucket sums transposed [d][j], padded
    __shared__ float rr [NB][NB + 1];    // sinkhorn matrix, padded
    __shared__ int   bstart[NB + 1];

    // ---- phase 0: bucket boundaries (segment_ids are sorted per row) ----
    const int* segb = seg + (size_t)b * T_LEN;
    if (tid == 0) { bstart[0] = 0; bstart[NB] = T_LEN; }
    for (int t = tid + 1; t < T_LEN; t += NTH) {
        int s  = segb[t];
        int sp = segb[t - 1];
        if (s != sp) {
            for (int x = sp + 1; x <= s; ++x) bstart[x] = t;  // handles skipped ids
        }
    }
    __syncthreads();

    // ---- phase 1: bucket sums of q and k (coalesced float4 streaming) ----
    const int rg = lane >> 4;     // row group 0..3
    const int l4 = lane & 15;     // dim quad 0..15
    const float* qb = q + ((size_t)b * T_LEN) * DH + l4 * 4;
    const float* kb = k + ((size_t)b * T_LEN) * DH + l4 * 4;

    for (int j = wave; j < NB; j += 8) {
        const int t0 = bstart[j], t1 = bstart[j + 1];
        float aq0 = 0.f, aq1 = 0.f, aq2 = 0.f, aq3 = 0.f;
        float ak0 = 0.f, ak1 = 0.f, ak2 = 0.f, ak3 = 0.f;
        #pragma unroll 2
        for (int t = t0 + rg; t < t1; t += 4) {
            const float4 vq = *reinterpret_cast<const float4*>(qb + (size_t)t * DH);
            const float4 vk = *reinterpret_cast<const float4*>(kb + (size_t)t * DH);
            aq0 += vq.x; aq1 += vq.y; aq2 += vq.z; aq3 += vq.w;
            ak0 += vk.x; ak1 += vk.y; ak2 += vk.z; ak3 += vk.w;
        }
        // reduce the 4 row-groups within the wave (xor bits 4 and 5 of lane)
        aq0 += __shfl_xor(aq0, 16); aq0 += __shfl_xor(aq0, 32);
        aq1 += __shfl_xor(aq1, 16); aq1 += __shfl_xor(aq1, 32);
        aq2 += __shfl_xor(aq2, 16); aq2 += __shfl_xor(aq2, 32);
        aq3 += __shfl_xor(aq3, 16); aq3 += __shfl_xor(aq3, 32);
        ak0 += __shfl_xor(ak0, 16); ak0 += __shfl_xor(ak0, 32);
        ak1 += __shfl_xor(ak1, 16); ak1 += __shfl_xor(ak1, 32);
        ak2 += __shfl_xor(ak2, 16); ak2 += __shfl_xor(ak2, 32);
        ak3 += __shfl_xor(ak3, 16); ak3 += __shfl_xor(ak3, 32);
        if (rg == 0) {
            const int d0 = l4 * 4;
            qs[j][d0 + 0] = aq0; qs[j][d0 + 1] = aq1;
            qs[j][d0 + 2] = aq2; qs[j][d0 + 3] = aq3;
            kst[d0 + 0][j] = ak0; kst[d0 + 1][j] = ak1;
            kst[d0 + 2][j] = ak2; kst[d0 + 3][j] = ak3;
        }
    }
    __syncthreads();

    // ---- phase 2+3: R = qs . ks^T / sqrt(64); r = (log(relu(R)+eps)+gumbel)/temp ----
    const float* ub = u + (size_t)b * NB * NB;
    for (int e = tid; e < NB * NB; e += NTH) {
        const int i = e >> 6;      // wave-uniform
        const int j = e & 63;      // = lane
        float dot = 0.f;
        #pragma unroll
        for (int d = 0; d < DH; ++d)
            dot = fmaf(qs[i][d], kst[d][j], dot);   // qs broadcast, kst conflict-free
        const float R   = dot * 0.125f;             // 1/sqrt(64)
        const float uu  = ub[e];
        const float gum = -logf(-logf(uu + EPS) + EPS);
        rr[i][j] = (logf(fmaxf(R, 0.f) + EPS) + gum) * (1.0f / 0.7f);
    }
    __syncthreads();

    // ---- phase 4: 8 sinkhorn iterations (row LSE then col LSE) ----
    for (int it = 0; it < 8; ++it) {
        // subtract logsumexp over axis 2 (j): wave handles rows wave, wave+8, ...
        for (int i = wave; i < NB; i += 8) {
            const float v = rr[i][lane];
            float mx = v;
            #pragma unroll
            for (int m = 1; m < 64; m <<= 1) mx = fmaxf(mx, __shfl_xor(mx, m));
            float s = __expf(v - mx);
            #pragma unroll
            for (int m = 1; m < 64; m <<= 1) s += __shfl_xor(s, m);
            rr[i][lane] = v - (mx + __logf(s));
        }
        __syncthreads();
        // subtract logsumexp over axis 1 (i): wave handles cols wave, wave+8, ...
        for (int j = wave; j < NB; j += 8) {
            const float v = rr[lane][j];
            float mx = v;
            #pragma unroll
            for (int m = 1; m < 64; m <<= 1) mx = fmaxf(mx, __shfl_xor(mx, m));
            float s = __expf(v - mx);
            #pragma unroll
            for (int m = 1; m < 64; m <<= 1) s += __shfl_xor(s, m);
            rr[lane][j] = v - (mx + __logf(s));
        }
        __syncthreads();
    }

    // ---- phase 5: out = exp(r) ----
    float* ob = out + (size_t)b * NB * NB;
    for (int e = tid; e < NB * NB; e += NTH)
        ob[e] = expf(rr[e >> 6][e & 63]);
}

extern "C" void kernel_launch(void* const* d_in, const int* in_sizes, int n_in,
                              void* d_out, int out_size, void* d_ws, size_t ws_size,
                              hipStream_t stream)
{
    (void)in_sizes; (void)n_in; (void)d_ws; (void)ws_size; (void)out_size;
    const float* q   = (const float*)d_in[0];
    const float* k   = (const float*)d_in[1];
    const int*   seg = (const int*)  d_in[2];
    const float* u   = (const float*)d_in[3];
    float*       out = (float*)d_out;

    sortnet_fused<<<dim3(256), dim3(NTH), 0, stream>>>(q, k, seg, u, out);
}